// Round 16
// baseline (241.541 us; speedup 1.0000x reference)
//
#include <hip/hip_runtime.h>

#define NTOK 2048
#define NEXP 8
#define TOPK 2
#define NITEM 4096   // NTOK*TOPK
#define DIM 1024
#define HID 2816
#define CAP 4096
#define LDP 72       // fallback-path padded LDS stride (u16)

typedef unsigned short u16;
typedef __bf16 bf16x8 __attribute__((ext_vector_type(8)));
typedef float f32x4 __attribute__((ext_vector_type(4)));

__device__ __forceinline__ u16 f2bf(float f) {
  unsigned u = __float_as_uint(f);
  return (u16)((u + 0x7FFFu + ((u >> 16) & 1u)) >> 16);
}
__device__ __forceinline__ unsigned pk2(float a, float b) {
  return (unsigned)f2bf(a) | ((unsigned)f2bf(b) << 16);
}
__device__ __forceinline__ void async16(const void* g, void* l) {
  __builtin_amdgcn_global_load_lds(
      (const __attribute__((address_space(1))) unsigned int*)g,
      (__attribute__((address_space(3))) unsigned int*)l, 16, 0, 0);
}
// 128B-row tile fragment ptr (BK=64 over k), XOR swizzle (row&7)<<4 — verified 0 conflicts.
__device__ __forceinline__ const bf16x8* fragpA(const u16* base, int row, int ko) {
  int byte = ((row << 7) + (ko << 1)) ^ ((row & 7) << 4);
  return (const bf16x8*)((const char*)base + byte);
}
// 64B-row tile fragment ptr (BK=32), XOR swizzle ((row>>1)&3)<<4 — verified 0 conflicts.
__device__ __forceinline__ const bf16x8* fragpB(const u16* base, int row, int kg) {
  int byte = (row << 6) + ((kg << 4) ^ (((row >> 1) & 3) << 4));
  return (const bf16x8*)((const char*)base + byte);
}
// pack 8 f32 -> 8 bf16 and store 16B
__device__ __forceinline__ void cvst8(const float4& a, const float4& b, void* dst) {
  union { __bf16 h[8]; uint4 q; } u;
  u.h[0] = (__bf16)a.x; u.h[1] = (__bf16)a.y; u.h[2] = (__bf16)a.z; u.h[3] = (__bf16)a.w;
  u.h[4] = (__bf16)b.x; u.h[5] = (__bf16)b.y; u.h[6] = (__bf16)b.z; u.h[7] = (__bf16)b.w;
  *(uint4*)dst = u.q;
}

__global__ void zero8(int* counts) {
  if (threadIdx.x < NEXP) counts[threadIdx.x] = 0;
}

__global__ void bucket(const int* __restrict__ ei, int* counts, int* lists) {
  int item = blockIdx.x * 256 + threadIdx.x;
  if (item < NITEM) {
    int e = ei[item] & 7;
    int pos = atomicAdd(&counts[e], 1);
    if (pos < CAP) lists[e * CAP + pos] = item;
  }
}

// f32 -> bf16 convert, 8 elems/thread
__global__ __launch_bounds__(256) void cvt8(const float* __restrict__ src,
                                            u16* __restrict__ dst, int n8) {
  int i = blockIdx.x * 256 + threadIdx.x;
  if (i >= n8) return;
  float4 v0 = *(const float4*)(src + (size_t)i * 8);
  float4 v1 = *(const float4*)(src + (size_t)i * 8 + 4);
  uint4 u;
  u.x = pk2(v0.x, v0.y); u.y = pk2(v0.z, v0.w);
  u.z = pk2(v1.x, v1.y); u.w = pk2(v1.z, v1.w);
  *(uint4*)(dst + (size_t)i * 8) = u;
}

// ---------------- Path A ----------------

// GEMM1 (R13-verified, 130 us): BM=256, BN=64, BK=32. Counted-vmcnt raw-barrier
// pipeline. (256,2) mandatory (R12: (256,3) spills the 128-AGPR acc).
// 3D grid dim3(44,16,8), n FASTEST — consecutive blocks share A token-rows (L2 hit);
// R15 measured the 1D m-slowest remap at +15 us. Do not change the grid again.
__global__ __launch_bounds__(256, 2) void gemm1H(
    const u16* __restrict__ xb, const float* __restrict__ w1,
    const float* __restrict__ w3, const int* __restrict__ counts,
    const int* __restrict__ lists, u16* __restrict__ G) {
  __shared__ __align__(16) u16 As[2][256 * 32];   // 16 KB each
  __shared__ __align__(16) u16 B1s[2][64 * 32];   // 4 KB each
  __shared__ __align__(16) u16 B3s[2][64 * 32];
  __shared__ int toks[256];

  const int e = blockIdx.z;
  int cnt = counts[e];
  if ((unsigned)cnt > CAP) cnt = 0;
  const int m0 = blockIdx.y * 256;
  if (m0 >= cnt) return;
  const int n0 = blockIdx.x * 64;
  const int tid = threadIdx.x;

  {
    int r = m0 + tid;
    int it = lists[e * CAP + (r < cnt ? r : 0)];
    toks[tid] = ((unsigned)it < NITEM) ? it : 0;
  }
  __syncthreads();

  const int lane = tid & 63;
  const int wrow = (tid >> 6) * 64;   // 4 m-waves
  const int lr = lane & 15;
  const int kg = lane >> 4;

  const int prow = tid >> 2;                       // 0..63
  const int q = tid & 3;
  const int ascol = (q ^ ((prow >> 1) & 3)) * 8;   // pre-swizzled source col
  const u16* xs[4];
#pragma unroll
  for (int p = 0; p < 4; ++p)
    xs[p] = xb + (size_t)(toks[p * 64 + prow] >> 1) * DIM + ascol;  // item -> token

  const int br = prow;
  const float* w1p = w1 + ((size_t)e * HID + n0 + br) * DIM + q * 8;
  const float* w3p = w3 + ((size_t)e * HID + n0 + br) * DIM + q * 8;
  const int bby = (br << 6) + ((q << 4) ^ (((br >> 1) & 3) << 4));

  float4 b1r[2][2], b3r[2][2];    // [set][chunk], static indexing only
  f32x4 acc1[4][4] = {};
  f32x4 acc3[4][4] = {};

#define KCL(k) ((k) < DIM ? (k) : (DIM - 32))
#define G1_LOADB(set, k)                                  \
  {                                                       \
    b1r[set][0] = *(const float4*)(w1p + (k));            \
    b1r[set][1] = *(const float4*)(w1p + (k) + 4);        \
    b3r[set][0] = *(const float4*)(w3p + (k));            \
    b3r[set][1] = *(const float4*)(w3p + (k) + 4);        \
  }
#define G1_STGA(buf, k)                                   \
  {                                                       \
    char* aD = (char*)As[buf] + tid * 16;                 \
    async16(xs[0] + (k), aD);                             \
    async16(xs[1] + (k), aD + 4096);                      \
    async16(xs[2] + (k), aD + 8192);                      \
    async16(xs[3] + (k), aD + 12288);                     \
  }
#define G1_WRITEB(buf, set)                                   \
  {                                                           \
    cvst8(b1r[set][0], b1r[set][1], (char*)B1s[buf] + bby);   \
    cvst8(b3r[set][0], b3r[set][1], (char*)B3s[buf] + bby);   \
  }
#define G1_COMP(cb)                                                          \
  {                                                                          \
    bf16x8 a[4];                                                             \
    _Pragma("unroll") for (int m = 0; m < 4; ++m)                            \
        a[m] = *fragpB(As[cb], wrow + m * 16 + lr, kg);                      \
    _Pragma("unroll") for (int n = 0; n < 4; ++n) {                          \
      bf16x8 b1 = *fragpB(B1s[cb], n * 16 + lr, kg);                         \
      bf16x8 b3 = *fragpB(B3s[cb], n * 16 + lr, kg);                         \
      _Pragma("unroll") for (int m = 0; m < 4; ++m) {                        \
        acc1[m][n] = __builtin_amdgcn_mfma_f32_16x16x32_bf16(a[m], b1, acc1[m][n], 0, 0, 0); \
        acc3[m][n] = __builtin_amdgcn_mfma_f32_16x16x32_bf16(a[m], b3, acc3[m][n], 0, 0, 0); \
      }                                                                      \
    }                                                                        \
  }
// vmcnt(4) at end drains A_{i+1} (older 4), keeps B_{i+2} (newest 4) in flight.
#define G1_ITER(i, cb)                                               \
  {                                                                  \
    G1_STGA(cb ^ 1, KCL(32 * ((i) + 1)));                            \
    G1_WRITEB(cb ^ 1, cb ^ 1); /* B_{i+1} regs -> LDS */             \
    __builtin_amdgcn_sched_barrier(0);                               \
    G1_LOADB(cb, KCL(32 * ((i) + 2)));                               \
    __builtin_amdgcn_sched_barrier(0);                               \
    G1_COMP(cb);                                                     \
    asm volatile("s_waitcnt vmcnt(4) lgkmcnt(0)" ::: "memory");      \
    __builtin_amdgcn_sched_barrier(0);                               \
    __builtin_amdgcn_s_barrier();                                    \
    __builtin_amdgcn_sched_barrier(0);                               \
  }

  // prologue: B0 -> set0, A0 -> buf0, B1 -> set1; drain B0+A0; write B0 to LDS0.
  G1_LOADB(0, 0);
  __builtin_amdgcn_sched_barrier(0);
  G1_STGA(0, 0);
  __builtin_amdgcn_sched_barrier(0);
  G1_LOADB(1, 32);
  asm volatile("s_waitcnt vmcnt(4)" ::: "memory");   // drain B0(4)+A0(4); B1 stays
  __builtin_amdgcn_sched_barrier(0);
  G1_WRITEB(0, 0);
  asm volatile("s_waitcnt lgkmcnt(0)" ::: "memory");
  __builtin_amdgcn_sched_barrier(0);
  __builtin_amdgcn_s_barrier();
  __builtin_amdgcn_sched_barrier(0);

  for (int i = 0; i < 32; i += 2) {
    G1_ITER(i, 0);
    G1_ITER(i + 1, 1);
  }
#undef G1_ITER
#undef G1_COMP
#undef G1_WRITEB
#undef G1_STGA
#undef G1_LOADB
#undef KCL

#pragma unroll
  for (int m = 0; m < 4; ++m) {
#pragma unroll
    for (int r = 0; r < 4; ++r) {
      const int row = wrow + m * 16 + kg * 4 + r;
      if (m0 + row < cnt) {
        const int it = toks[row];
        u16* gp = G + (size_t)it * HID + n0 + lr;
#pragma unroll
        for (int n = 0; n < 4; ++n) {
          float v1 = acc1[m][n][r];
          float v3 = acc3[m][n][r];
          float s = v1 / (1.f + __expf(-v1)) * v3;
          gp[n * 16] = f2bf(s);
        }
      }
    }
  }
}

// GEMM2 fused-transpose (R15-measured): out[item][d] = G[item][:] . w2[e][:][d].
// BM=128, BN=64, BK=64, 3 blocks/CU. A (G bf16) via global_load_lds pre-swizzled;
// B: w2 f32 quads 2-ahead to regs, transpose-scattered to LDS u16. Counted vmcnt.
__global__ __launch_bounds__(256, 3) void gemm2T(
    const u16* __restrict__ G, const float* __restrict__ w2,
    const int* __restrict__ counts, const int* __restrict__ lists,
    float* __restrict__ out) {
  __shared__ __align__(16) u16 As[2][128 * 64];   // 16 KB each
  __shared__ __align__(16) u16 Bs[2][64 * 64];    // 8 KB each
  __shared__ int toks[128];

  const int flat = blockIdx.x;          // n + 16*(e + 8*m)
  const int n_id = flat & 15;
  const int t2 = flat >> 4;
  const int e = t2 & 7;
  const int m_id = t2 >> 3;

  int cnt = counts[e];
  if ((unsigned)cnt > CAP) cnt = 0;
  const int m0 = m_id * 128;
  if (m0 >= cnt) return;
  const int n0 = n_id * 64;
  const int tid = threadIdx.x;

  if (tid < 128) {
    int r = m0 + tid;
    int it = lists[e * CAP + (r < cnt ? r : 0)];
    toks[tid] = ((unsigned)it < NITEM) ? it : 0;
  }
  __syncthreads();

  const int lane = tid & 63;
  const int wid = tid >> 6;
  const int wr = (wid >> 1) * 64;   // {0,64}
  const int wc = (wid & 1) * 32;    // {0,32}
  const int lr = lane & 15;
  const int kg = lane >> 4;

  // A staging: srow 0..31, chunk c 0..7; rows srow+32p, p=0..3.
  const int srow = tid >> 3;
  const int c = tid & 7;
  const int scol = ((c ^ (srow & 7)) * 8);
  const u16* as[4];
#pragma unroll
  for (int p = 0; p < 4; ++p)
    as[p] = G + (size_t)toks[p * 32 + srow] * HID + scol;

  // B: h = tid&63 (k-row), tg = tid>>6; quads at d_local = tg*4 + qq*16.
  const int h = tid & 63;
  const int tg = tid >> 6;
  const float* w2p = w2 + ((size_t)e * HID + h) * DIM + n0 + tg * 4;

  float4 bq[2][4];   // [set][quad], static indexing only
  f32x4 acc[4][2] = {};

#define KCL2(k) ((k) < HID ? (k) : (HID - 64))
#define G2_LOADB(set, k)                                           \
  {                                                                \
    _Pragma("unroll") for (int qq = 0; qq < 4; ++qq)               \
        bq[set][qq] = *(const float4*)(w2p + (size_t)(k) * DIM + qq * 16); \
  }
#define G2_STGA(buf, k)                                            \
  {                                                                \
    char* aD = (char*)As[buf] + tid * 16;                          \
    _Pragma("unroll") for (int p = 0; p < 4; ++p)                  \
        async16(as[p] + (k), aD + p * 4096);                       \
  }
#define G2_WB1(buf, qq, jj, val)                                             \
  {                                                                          \
    int d_ = tg * 4 + (qq) * 16 + (jj);                                      \
    int by_ = ((d_ << 7) + (h << 1)) ^ ((d_ & 7) << 4);                      \
    *(u16*)((char*)Bs[buf] + by_) = f2bf(val);                               \
  }
#define G2_WRITEB(buf, set)                                  \
  {                                                          \
    _Pragma("unroll") for (int qq = 0; qq < 4; ++qq) {       \
      G2_WB1(buf, qq, 0, bq[set][qq].x);                     \
      G2_WB1(buf, qq, 1, bq[set][qq].y);                     \
      G2_WB1(buf, qq, 2, bq[set][qq].z);                     \
      G2_WB1(buf, qq, 3, bq[set][qq].w);                     \
    }                                                        \
  }
#define G2_COMP(cb)                                                          \
  {                                                                          \
    _Pragma("unroll") for (int kk = 0; kk < 2; ++kk) {                       \
      const int ko = kk * 32 + kg * 8;                                       \
      bf16x8 a[4], b[2];                                                     \
      _Pragma("unroll") for (int m = 0; m < 4; ++m)                          \
          a[m] = *fragpA(As[cb], wr + m * 16 + lr, ko);                      \
      _Pragma("unroll") for (int n = 0; n < 2; ++n)                          \
          b[n] = *fragpA(Bs[cb], wc + n * 16 + lr, ko);                      \
      _Pragma("unroll") for (int n = 0; n < 2; ++n)                          \
          _Pragma("unroll") for (int m = 0; m < 4; ++m)                      \
              acc[m][n] = __builtin_amdgcn_mfma_f32_16x16x32_bf16(a[m], b[n], acc[m][n], 0, 0, 0); \
    }                                                                        \
  }
#define G2_IT(I, PB, CB)                                             \
  {                                                                  \
    G2_STGA(PB, KCL2(64 * ((I) + 1)));                               \
    __builtin_amdgcn_sched_barrier(0);                               \
    asm volatile("s_waitcnt vmcnt(4)" ::: "memory");                 \
    __builtin_amdgcn_sched_barrier(0);                               \
    G2_WRITEB(PB, PB);                                               \
    G2_LOADB(CB, KCL2(64 * ((I) + 2)));                              \
    __builtin_amdgcn_sched_barrier(0);                               \
    G2_COMP(CB);                                                     \
    asm volatile("s_waitcnt vmcnt(4) lgkmcnt(0)" ::: "memory");      \
    __builtin_amdgcn_sched_barrier(0);                               \
    __builtin_amdgcn_s_barrier();                                    \
    __builtin_amdgcn_sched_barrier(0);                               \
  }

  // prologue: B0 regs, A0 lds, B1 regs; drain B0+A0 (keep B1); write B0 to LDS.
  G2_LOADB(0, 0);
  G2_STGA(0, 0);
  G2_LOADB(1, 64);
  __builtin_amdgcn_sched_barrier(0);
  asm volatile("s_waitcnt vmcnt(4)" ::: "memory");
  __builtin_amdgcn_sched_barrier(0);
  G2_WRITEB(0, 0);
  asm volatile("s_waitcnt lgkmcnt(0)" ::: "memory");
  __builtin_amdgcn_sched_barrier(0);
  __builtin_amdgcn_s_barrier();
  __builtin_amdgcn_sched_barrier(0);

  for (int i = 0; i < 44; i += 2) {
    G2_IT(i, 1, 0);
    G2_IT(i + 1, 0, 1);
  }
#undef G2_IT
#undef G2_COMP
#undef G2_WRITEB
#undef G2_WB1
#undef G2_STGA
#undef G2_LOADB
#undef KCL2

#pragma unroll
  for (int m = 0; m < 4; ++m) {
#pragma unroll
    for (int r = 0; r < 4; ++r) {
      const int row = wr + m * 16 + kg * 4 + r;
      if (m0 + row < cnt) {
        const int it = toks[row];
        float* op = out + (size_t)it * DIM + n0 + wc + lr;
#pragma unroll
        for (int n = 0; n < 2; ++n)
          op[n * 16] = acc[m][n][r];
      }
    }
  }
}

// ---------------- Path B (fallback, small workspace): round-2 kernels ----------------

__global__ __launch_bounds__(256, 2) void gemm1B(
    const float* __restrict__ x, const float* __restrict__ w1,
    const float* __restrict__ w3, const int* __restrict__ counts,
    const int* __restrict__ lists, u16* __restrict__ G) {
  __shared__ __align__(16) u16 As[128 * LDP];
  __shared__ __align__(16) u16 B1s[128 * LDP];
  __shared__ __align__(16) u16 B3s[128 * LDP];
  __shared__ int toks[128];

  const int e = blockIdx.z;
  int cnt = counts[e];
  if ((unsigned)cnt > CAP) cnt = 0;
  const int m0 = blockIdx.y * 128;
  if (m0 >= cnt) return;
  const int n0 = blockIdx.x * 128;
  const int tid = threadIdx.x;

  if (tid < 128) {
    int r = m0 + tid;
    int it = lists[e * CAP + (r < cnt ? r : 0)];
    toks[tid] = ((unsigned)it < NITEM) ? it : 0;
  }
  __syncthreads();

  const int lane = tid & 63;
  const int wr = ((tid >> 7) & 1) * 64;
  const int wc = ((tid >> 6) & 1) * 64;
  const int lr = lane & 15;
  const int kg = lane >> 4;
  const int arow = tid >> 3;
  const int c8 = (tid & 7) * 8;

  const float* xsrc[4];
#pragma unroll
  for (int p = 0; p < 4; ++p)
    xsrc[p] = x + (size_t)(toks[p * 32 + arow] >> 1) * DIM + c8;
  const float* w1p = w1 + ((size_t)e * HID + n0 + arow) * DIM + c8;
  const float* w3p = w3 + ((size_t)e * HID + n0 + arow) * DIM + c8;

  f32x4 acc1[4][4] = {};
  f32x4 acc3[4][4] = {};

  for (int k0 = 0; k0 < DIM; k0 += 64) {
#pragma unroll
    for (int p = 0; p < 4; ++p) {
      float4 v0 = *(const float4*)(xsrc[p] + k0);
      float4 v1 = *(const float4*)(xsrc[p] + k0 + 4);
      uint4 u;
      u.x = pk2(v0.x, v0.y); u.y = pk2(v0.z, v0.w);
      u.z = pk2(v1.x, v1.y); u.w = pk2(v1.z, v1.w);
      *(uint4*)&As[(p * 32 + arow) * LDP + c8] = u;
    }
#pragma unroll
    for (int p = 0; p < 4; ++p) {
      float4 v0 = *(const float4*)(w1p + (size_t)(p * 32) * DIM + k0);
      float4 v1 = *(const float4*)(w1p + (size_t)(p * 32) * DIM + k0 + 4);
      uint4 u;
      u.x = pk2(v0.x, v0.y); u.y = pk2(v0.z, v0.w);
      u.z = pk2(v1.x, v1.y); u.w = pk2(v1.z, v1.w);
      *(uint4*)&B1s[(p * 32 + arow) * LDP + c8] = u;
      v0 = *(const float4*)(w3p + (size_t)(p * 32) * DIM + k0);
      v1 = *(const float4*)(w3p + (size_t)(p * 32) * DIM + k0 + 4);
      u.x = pk2(v0.x, v0.y); u.y = pk2(v0.z, v0.w);
      u.z = pk2(v1.x, v1.y); u.w = pk2(v1.z, v1.w);
      *(uint4*)&B3s[(p * 32 + arow) * LDP + c8] = u;
    }
    __syncthreads();
#pragma unroll
    for (int kk = 0; kk < 2; ++kk) {
      const int ko = kk * 32 + kg * 8;
      bf16x8 a[4];
#pragma unroll
      for (int m = 0; m < 4; ++m)
        a[m] = *(const bf16x8*)&As[(wr + m * 16 + lr) * LDP + ko];
#pragma unroll
      for (int n = 0; n < 4; ++n) {
        bf16x8 b1 = *(const bf16x8*)&B1s[(wc + n * 16 + lr) * LDP + ko];
        bf16x8 b3 = *(const bf16x8*)&B3s[(wc + n * 16 + lr) * LDP + ko];
#pragma unroll
        for (int m = 0; m < 4; ++m) {
          acc1[m][n] = __builtin_amdgcn_mfma_f32_16x16x32_bf16(a[m], b1, acc1[m][n], 0, 0, 0);
          acc3[m][n] = __builtin_amdgcn_mfma_f32_16x16x32_bf16(a[m], b3, acc3[m][n], 0, 0, 0);
        }
      }
    }
    __syncthreads();
  }

#pragma unroll
  for (int m = 0; m < 4; ++m) {
#pragma unroll
    for (int r = 0; r < 4; ++r) {
      const int row = wr + m * 16 + kg * 4 + r;
      if (m0 + row < cnt) {
        const int it = toks[row];
        u16* gp = G + (size_t)it * HID + n0 + wc + lr;
#pragma unroll
        for (int n = 0; n < 4; ++n) {
          float v1 = acc1[m][n][r];
          float v3 = acc3[m][n][r];
          float s = v1 / (1.f + __expf(-v1)) * v3;
          gp[n * 16] = f2bf(s);
        }
      }
    }
  }
}

__global__ __launch_bounds__(256, 2) void gemm2B(
    const u16* __restrict__ G, const float* __restrict__ w2,
    const int* __restrict__ counts, const int* __restrict__ lists,
    float* __restrict__ out) {
  __shared__ __align__(16) u16 As[128 * LDP];
  __shared__ __align__(16) u16 Bs[128 * LDP];
  __shared__ int toks[128];

  const int e = blockIdx.z;
  int cnt = counts[e];
  if ((unsigned)cnt > CAP) cnt = 0;
  const int m0 = blockIdx.y * 128;
  if (m0 >= cnt) return;
  const int n0 = blockIdx.x * 128;
  const int tid = threadIdx.x;

  if (tid < 128) {
    int r = m0 + tid;
    int it = lists[e * CAP + (r < cnt ? r : 0)];
    toks[tid] = ((unsigned)it < NITEM) ? it : 0;
  }
  __syncthreads();

  const int lane = tid & 63;
  const int wr = ((tid >> 7) & 1) * 64;
  const int wc = ((tid >> 6) & 1) * 64;
  const int lr = lane & 15;
  const int kg = lane >> 4;
  const int arow = tid >> 3;
  const int c8 = (tid & 7) * 8;
  const int brow = tid >> 5;
  const int d4 = (tid & 31) * 4;

  const u16* asrc[4];
#pragma unroll
  for (int p = 0; p < 4; ++p)
    asrc[p] = G + (size_t)toks[p * 32 + arow] * HID + c8;
  const float* bsrc = w2 + ((size_t)e * HID) * DIM + n0 + d4;

  f32x4 acc[4][4] = {};

  for (int k0 = 0; k0 < HID; k0 += 64) {
#pragma unroll
    for (int p = 0; p < 4; ++p) {
      uint4 u = *(const uint4*)(asrc[p] + k0);
      *(uint4*)&As[(p * 32 + arow) * LDP + c8] = u;
    }
#pragma unroll
    for (int p = 0; p < 8; ++p) {
      const int hl = p * 8 + brow;
      float4 v = *(const float4*)(bsrc + (size_t)(k0 + hl) * DIM);
      Bs[(d4 + 0) * LDP + hl] = f2bf(v.x);
      Bs[(d4 + 1) * LDP + hl] = f2bf(v.y);
      Bs[(d4 + 2) * LDP + hl] = f2bf(v.z);
      Bs[(d4 + 3) * LDP + hl] = f2bf(v.w);
    }
    __syncthreads();
#pragma unroll
    for (int kk = 0; kk < 2; ++kk) {
      const int ko = kk * 32 + kg * 8;
      bf16x8 a[4];
#pragma unroll
      for (int m = 0; m < 4; ++m)
        a[m] = *(const bf16x8*)&As[(wr + m * 16 + lr) * LDP + ko];
#pragma unroll
      for (int n = 0; n < 4; ++n) {
        bf16x8 b = *(const bf16x8*)&Bs[(wc + n * 16 + lr) * LDP + ko];
#pragma unroll
        for (int m = 0; m < 4; ++m)
          acc[m][n] = __builtin_amdgcn_mfma_f32_16x16x32_bf16(a[m], b, acc[m][n], 0, 0, 0);
      }
    }
    __syncthreads();
  }

#pragma unroll
  for (int m = 0; m < 4; ++m) {
#pragma unroll
    for (int r = 0; r < 4; ++r) {
      const int row = wr + m * 16 + kg * 4 + r;
      if (m0 + row < cnt) {
        const int it = toks[row];
        float* op = out + (size_t)it * DIM + n0 + wc + lr;
#pragma unroll
        for (int n = 0; n < 4; ++n)
          op[n * 16] = acc[m][n][r];
      }
    }
  }
}

extern "C" void kernel_launch(void* const* d_in, const int* in_sizes, int n_in,
                              void* d_out, int out_size, void* d_ws, size_t ws_size,
                              hipStream_t stream) {
  (void)in_sizes; (void)n_in; (void)out_size;
  const float* x  = (const float*)d_in[0];
  const int*   ei = (const int*)d_in[1];
  const float* w1 = (const float*)d_in[2];
  const float* w2 = (const float*)d_in[3];
  const float* w3 = (const float*)d_in[4];
  float* out = (float*)d_out;

  char* ws = (char*)d_ws;

  // Path A layout: G | xb | counts | lists  (~27.4 MB)
  const size_t oG = 0;
  const size_t oXB = 23068672u;
  const size_t oCNT = oXB + 4194304u;
  const size_t oLST = oCNT + 64u;
  const size_t needA = oLST + 131072u;

  if (ws_size >= needA) {
    u16* G      = (u16*)(ws + oG);
    u16* xb     = (u16*)(ws + oXB);
    int* counts = (int*)(ws + oCNT);
    int* lists  = (int*)(ws + oLST);

    zero8<<<1, 64, 0, stream>>>(counts);
    bucket<<<NITEM / 256, 256, 0, stream>>>(ei, counts, lists);
    cvt8<<<(NTOK * DIM / 8) / 256, 256, 0, stream>>>(x, xb, NTOK * DIM / 8);
    gemm1H<<<dim3(HID / 64, CAP / 256, NEXP), 256, 0, stream>>>(xb, w1, w3, counts, lists, G);
    gemm2T<<<16 * 8 * 32, 256, 0, stream>>>(G, w2, counts, lists, out);
  } else {
    // fallback: compact workspace, on-the-fly conversion (round-2 path)
    u16* G      = (u16*)ws;
    int* counts = (int*)(ws + 23068672u);
    int* lists  = (int*)(ws + 23068736u);

    zero8<<<1, 64, 0, stream>>>(counts);
    bucket<<<NITEM / 256, 256, 0, stream>>>(ei, counts, lists);
    gemm1B<<<dim3(HID / 128, CAP / 128, NEXP), 256, 0, stream>>>(x, w1, w3, counts, lists, G);
    gemm2B<<<dim3(DIM / 128, CAP / 128, NEXP), 256, 0, stream>>>(G, w2, counts, lists, out);
  }
}

// Round 17
// 199.191 us; speedup vs baseline: 1.2126x; 1.2126x over previous
//
#include <hip/hip_runtime.h>

#define NTOK 2048
#define NEXP 8
#define TOPK 2
#define NITEM 4096   // NTOK*TOPK
#define DIM 1024
#define HID 2816
#define CAP 4096
#define LDP 72       // fallback-path padded LDS stride (u16)

typedef unsigned short u16;
typedef __bf16 bf16x8 __attribute__((ext_vector_type(8)));
typedef float f32x4 __attribute__((ext_vector_type(4)));

__device__ __forceinline__ u16 f2bf(float f) {
  unsigned u = __float_as_uint(f);
  return (u16)((u + 0x7FFFu + ((u >> 16) & 1u)) >> 16);
}
__device__ __forceinline__ unsigned pk2(float a, float b) {
  return (unsigned)f2bf(a) | ((unsigned)f2bf(b) << 16);
}
__device__ __forceinline__ void async16(const void* g, void* l) {
  __builtin_amdgcn_global_load_lds(
      (const __attribute__((address_space(1))) unsigned int*)g,
      (__attribute__((address_space(3))) unsigned int*)l, 16, 0, 0);
}
// 128B-row tile fragment ptr (BK=64 over k), XOR swizzle (row&7)<<4 — verified 0 conflicts.
__device__ __forceinline__ const bf16x8* fragpA(const u16* base, int row, int ko) {
  int byte = ((row << 7) + (ko << 1)) ^ ((row & 7) << 4);
  return (const bf16x8*)((const char*)base + byte);
}
// 64B-row tile fragment ptr (BK=32), XOR swizzle ((row>>1)&3)<<4 — verified 0 conflicts.
__device__ __forceinline__ const bf16x8* fragpB(const u16* base, int row, int kg) {
  int byte = (row << 6) + ((kg << 4) ^ (((row >> 1) & 3) << 4));
  return (const bf16x8*)((const char*)base + byte);
}
// pack 8 f32 -> 8 bf16 and store 16B
__device__ __forceinline__ void cvst8(const float4& a, const float4& b, void* dst) {
  union { __bf16 h[8]; uint4 q; } u;
  u.h[0] = (__bf16)a.x; u.h[1] = (__bf16)a.y; u.h[2] = (__bf16)a.z; u.h[3] = (__bf16)a.w;
  u.h[4] = (__bf16)b.x; u.h[5] = (__bf16)b.y; u.h[6] = (__bf16)b.z; u.h[7] = (__bf16)b.w;
  *(uint4*)dst = u.q;
}

__global__ void zero8(int* counts) {
  if (threadIdx.x < NEXP) counts[threadIdx.x] = 0;
}

__global__ void bucket(const int* __restrict__ ei, int* counts, int* lists) {
  int item = blockIdx.x * 256 + threadIdx.x;
  if (item < NITEM) {
    int e = ei[item] & 7;
    int pos = atomicAdd(&counts[e], 1);
    if (pos < CAP) lists[e * CAP + pos] = item;
  }
}

// f32 -> bf16 convert, 8 elems/thread
__global__ __launch_bounds__(256) void cvt8(const float* __restrict__ src,
                                            u16* __restrict__ dst, int n8) {
  int i = blockIdx.x * 256 + threadIdx.x;
  if (i >= n8) return;
  float4 v0 = *(const float4*)(src + (size_t)i * 8);
  float4 v1 = *(const float4*)(src + (size_t)i * 8 + 4);
  uint4 u;
  u.x = pk2(v0.x, v0.y); u.y = pk2(v0.z, v0.w);
  u.z = pk2(v1.x, v1.y); u.w = pk2(v1.z, v1.w);
  *(uint4*)(dst + (size_t)i * 8) = u;
}

// w2 [E][H][D] f32 -> w2t [E][D][H] bf16, 64x64 LDS tile transpose
__global__ __launch_bounds__(256) void tw2(const float* __restrict__ w2, u16* __restrict__ w2t) {
  __shared__ float tile[64][65];
  const int e = blockIdx.z;
  const int h0 = blockIdx.y * 64;
  const int d0 = blockIdx.x * 64;
  const int tid = threadIdx.x;
  const int r = tid >> 4, c = (tid & 15) * 4;
  const float* src = w2 + (size_t)e * HID * DIM;
#pragma unroll
  for (int p = 0; p < 4; ++p) {
    float4 v = *(const float4*)(src + (size_t)(h0 + p * 16 + r) * DIM + d0 + c);
    tile[p * 16 + r][c] = v.x;
    tile[p * 16 + r][c + 1] = v.y;
    tile[p * 16 + r][c + 2] = v.z;
    tile[p * 16 + r][c + 3] = v.w;
  }
  __syncthreads();
  u16* dst = w2t + (size_t)e * DIM * HID;
#pragma unroll
  for (int p = 0; p < 4; ++p) {
    int dd = p * 16 + r;
    uint2 pkv;
    pkv.x = pk2(tile[c][dd], tile[c + 1][dd]);
    pkv.y = pk2(tile[c + 2][dd], tile[c + 3][dd]);
    *(uint2*)(dst + (size_t)(d0 + dd) * HID + h0 + c) = pkv;
  }
}

// ---------------- Path A (R11 configuration — best measured total 199.5 us) ----------------

// GEMM1: BM=256, BN=64, BK=32. 3-buffer A (global_load_lds, 2 iters ahead),
// B f32->reg 2-ahead -> bf16 LDS 1-ahead. Counted vmcnt, raw barriers.
// 1D grid, m SLOWEST.
__global__ __launch_bounds__(256, 2) void gemm1I(
    const u16* __restrict__ xb, const float* __restrict__ w1,
    const float* __restrict__ w3, const int* __restrict__ counts,
    const int* __restrict__ lists, u16* __restrict__ G) {
  __shared__ __align__(16) u16 As[3][256 * 32];   // 16 KB each
  __shared__ __align__(16) u16 B1s[2][64 * 32];   // 4 KB each
  __shared__ __align__(16) u16 B3s[2][64 * 32];
  __shared__ int toks[256];

  const int flat = blockIdx.x;           // 44 * (z + 8*m)
  const int n_id = flat % 44;
  const int t2 = flat / 44;
  const int e = t2 & 7;
  const int m_id = t2 >> 3;

  int cnt = counts[e];
  if ((unsigned)cnt > CAP) cnt = 0;
  const int m0 = m_id * 256;
  if (m0 >= cnt) return;
  const int n0 = n_id * 64;
  const int tid = threadIdx.x;

  {
    int r = m0 + tid;
    int it = lists[e * CAP + (r < cnt ? r : 0)];
    toks[tid] = ((unsigned)it < NITEM) ? it : 0;
  }
  __syncthreads();

  const int lane = tid & 63;
  const int wrow = (tid >> 6) * 64;   // 4 m-waves
  const int lr = lane & 15;
  const int kg = lane >> 4;

  const int prow = tid >> 2;                       // 0..63
  const int q = tid & 3;
  const int ascol = (q ^ ((prow >> 1) & 3)) * 8;   // pre-swizzled source col
  const u16* xs[4];
#pragma unroll
  for (int p = 0; p < 4; ++p)
    xs[p] = xb + (size_t)(toks[p * 64 + prow] >> 1) * DIM + ascol;  // item -> token

  const int br = prow;
  const float* w1p = w1 + ((size_t)e * HID + n0 + br) * DIM + q * 8;
  const float* w3p = w3 + ((size_t)e * HID + n0 + br) * DIM + q * 8;
  const int bby = (br << 6) + ((q << 4) ^ (((br >> 1) & 3) << 4));

  float4 b1r[2][2], b3r[2][2];    // [set][chunk], static indexing only
  f32x4 acc1[4][4] = {};
  f32x4 acc3[4][4] = {};

#define KCL(k) ((k) < DIM ? (k) : (DIM - 32))
#define G1_LOADB(set, k)                                  \
  {                                                       \
    b1r[set][0] = *(const float4*)(w1p + (k));            \
    b1r[set][1] = *(const float4*)(w1p + (k) + 4);        \
    b3r[set][0] = *(const float4*)(w3p + (k));            \
    b3r[set][1] = *(const float4*)(w3p + (k) + 4);        \
  }
#define G1_STGA(buf, k)                                   \
  {                                                       \
    char* aD = (char*)As[buf] + tid * 16;                 \
    async16(xs[0] + (k), aD);                             \
    async16(xs[1] + (k), aD + 4096);                      \
    async16(xs[2] + (k), aD + 8192);                      \
    async16(xs[3] + (k), aD + 12288);                     \
  }
#define G1_WRITEB(buf, set)                                   \
  {                                                           \
    cvst8(b1r[set][0], b1r[set][1], (char*)B1s[buf] + bby);   \
    cvst8(b3r[set][0], b3r[set][1], (char*)B3s[buf] + bby);   \
  }
#define G1_COMP(ab, bb)                                                      \
  {                                                                          \
    bf16x8 a[4];                                                             \
    _Pragma("unroll") for (int m = 0; m < 4; ++m)                            \
        a[m] = *fragpB(As[ab], wrow + m * 16 + lr, kg);                      \
    _Pragma("unroll") for (int n = 0; n < 4; ++n) {                          \
      bf16x8 b1 = *fragpB(B1s[bb], n * 16 + lr, kg);                         \
      bf16x8 b3 = *fragpB(B3s[bb], n * 16 + lr, kg);                         \
      _Pragma("unroll") for (int m = 0; m < 4; ++m) {                        \
        acc1[m][n] = __builtin_amdgcn_mfma_f32_16x16x32_bf16(a[m], b1, acc1[m][n], 0, 0, 0); \
        acc3[m][n] = __builtin_amdgcn_mfma_f32_16x16x32_bf16(a[m], b3, acc3[m][n], 0, 0, 0); \
      }                                                                      \
    }                                                                        \
  }
// AC = I%3 (compute A buf), AS2 = (I+2)%3 (stage A buf),
// BC = I%2 (compute B buf + load reg-set), BW = (I+1)%2 (write B buf/reg-set).
#define G1_ITER(I, AC, AS2, BC, BW)                                  \
  {                                                                  \
    G1_STGA(AS2, KCL(32 * ((I) + 2)));                               \
    __builtin_amdgcn_sched_barrier(0);                               \
    asm volatile("s_waitcnt vmcnt(4)" ::: "memory");                 \
    __builtin_amdgcn_sched_barrier(0);                               \
    G1_WRITEB(BW, BW);                                               \
    G1_LOADB(BC, KCL(32 * ((I) + 2)));                               \
    __builtin_amdgcn_sched_barrier(0);                               \
    G1_COMP(AC, BC);                                                 \
    asm volatile("s_waitcnt lgkmcnt(0)" ::: "memory");               \
    __builtin_amdgcn_sched_barrier(0);                               \
    __builtin_amdgcn_s_barrier();                                    \
    __builtin_amdgcn_sched_barrier(0);                               \
  }

  // prologue: B0,A0,B1,A1 issued; drain B0+A0 (keep B1+A1); stage B0 to LDS.
  G1_LOADB(0, 0);
  G1_STGA(0, 0);
  G1_LOADB(1, 32);
  G1_STGA(1, 32);
  __builtin_amdgcn_sched_barrier(0);
  asm volatile("s_waitcnt vmcnt(8)" ::: "memory");
  __builtin_amdgcn_sched_barrier(0);
  G1_WRITEB(0, 0);
  asm volatile("s_waitcnt lgkmcnt(0)" ::: "memory");
  __builtin_amdgcn_sched_barrier(0);
  __builtin_amdgcn_s_barrier();
  __builtin_amdgcn_sched_barrier(0);

  for (int i = 0; i < 30; i += 6) {
    G1_ITER(i + 0, 0, 2, 0, 1);
    G1_ITER(i + 1, 1, 0, 1, 0);
    G1_ITER(i + 2, 2, 1, 0, 1);
    G1_ITER(i + 3, 0, 2, 1, 0);
    G1_ITER(i + 4, 1, 0, 0, 1);
    G1_ITER(i + 5, 2, 1, 1, 0);
  }
  G1_ITER(30, 0, 2, 0, 1);
  G1_ITER(31, 1, 0, 1, 0);
#undef G1_ITER
#undef G1_COMP
#undef G1_WRITEB
#undef G1_STGA
#undef G1_LOADB
#undef KCL

#pragma unroll
  for (int m = 0; m < 4; ++m) {
#pragma unroll
    for (int r = 0; r < 4; ++r) {
      const int row = wrow + m * 16 + kg * 4 + r;
      if (m0 + row < cnt) {
        const int it = toks[row];
        u16* gp = G + (size_t)it * HID + n0 + lr;
#pragma unroll
        for (int n = 0; n < 4; ++n) {
          float v1 = acc1[m][n][r];
          float v3 = acc3[m][n][r];
          float s = v1 / (1.f + __expf(-v1)) * v3;
          gp[n * 16] = f2bf(s);
        }
      }
    }
  }
}

// GEMM2: out[item][d] = G[item][:] . w2t[e][d][:] — 128x64 tile, BK=64, dbuf 2-phase,
// both operands global_load_lds with verified conflict-free swizzle.
// 1D grid, m slowest (dispatch-contiguous active blocks).
__global__ __launch_bounds__(256, 3) void gemm2F(
    const u16* __restrict__ G, const u16* __restrict__ w2t,
    const int* __restrict__ counts, const int* __restrict__ lists,
    float* __restrict__ out) {
  __shared__ __align__(16) u16 As[2][128 * 64];  // 16 KB each
  __shared__ __align__(16) u16 Bs[2][64 * 64];   // 8 KB each
  __shared__ int toks[128];

  const int flat = blockIdx.x;          // 16 * (e + 8*m)
  const int n_id = flat & 15;
  const int t2 = flat >> 4;
  const int e = t2 & 7;
  const int m_id = t2 >> 3;

  int cnt = counts[e];
  if ((unsigned)cnt > CAP) cnt = 0;
  const int m0 = m_id * 128;
  if (m0 >= cnt) return;
  const int n0 = n_id * 64;
  const int tid = threadIdx.x;

  if (tid < 128) {
    int r = m0 + tid;
    int it = lists[e * CAP + (r < cnt ? r : 0)];
    toks[tid] = ((unsigned)it < NITEM) ? it : 0;
  }
  __syncthreads();

  const int lane = tid & 63;
  const int wid = tid >> 6;
  const int wr = (wid >> 1) * 64;   // {0,64}
  const int wc = (wid & 1) * 32;    // {0,32}
  const int lr = lane & 15;
  const int kg = lane >> 4;

  const int srow = tid >> 3;                       // 0..31
  const int scol = ((tid & 7) ^ (srow & 7)) * 8;   // pre-swizzled source col (128B rows)

  const u16* as0 = G + (size_t)toks[srow] * HID + scol;
  const u16* as1 = G + (size_t)toks[32 + srow] * HID + scol;
  const u16* as2 = G + (size_t)toks[64 + srow] * HID + scol;
  const u16* as3 = G + (size_t)toks[96 + srow] * HID + scol;
  const u16* bs0 = w2t + ((size_t)e * DIM + n0 + srow) * HID + scol;
  const u16* bs1 = bs0 + (size_t)32 * HID;

  f32x4 acc[4][2] = {};

#define STG2(buf, k)                          \
  {                                           \
    char* aD = (char*)As[buf] + tid * 16;     \
    char* bD = (char*)Bs[buf] + tid * 16;     \
    async16(as0 + (k), aD);                   \
    async16(as1 + (k), aD + 4096);            \
    async16(as2 + (k), aD + 8192);            \
    async16(as3 + (k), aD + 12288);           \
    async16(bs0 + (k), bD);                   \
    async16(bs1 + (k), bD + 4096);            \
  }

  STG2(0, 0);
  __syncthreads();

  int cur = 0;
  for (int k0 = 0; k0 < HID; k0 += 64) {
    if (k0 + 64 < HID) STG2(cur ^ 1, k0 + 64);
    const u16* Ab = As[cur];
    const u16* Bb = Bs[cur];
#pragma unroll
    for (int kk = 0; kk < 2; ++kk) {
      const int ko = kk * 32 + kg * 8;
      bf16x8 a[4], b[2];
#pragma unroll
      for (int m = 0; m < 4; ++m) a[m] = *fragpA(Ab, wr + m * 16 + lr, ko);
#pragma unroll
      for (int n = 0; n < 2; ++n) b[n] = *fragpA(Bb, wc + n * 16 + lr, ko);
#pragma unroll
      for (int n = 0; n < 2; ++n)
#pragma unroll
        for (int m = 0; m < 4; ++m)
          acc[m][n] = __builtin_amdgcn_mfma_f32_16x16x32_bf16(a[m], b[n], acc[m][n], 0, 0, 0);
    }
    __syncthreads();
    cur ^= 1;
  }
#undef STG2

#pragma unroll
  for (int m = 0; m < 4; ++m) {
#pragma unroll
    for (int r = 0; r < 4; ++r) {
      const int row = wr + m * 16 + kg * 4 + r;
      if (m0 + row < cnt) {
        const int it = toks[row];
        float* op = out + (size_t)it * DIM + n0 + wc + lr;
#pragma unroll
        for (int n = 0; n < 2; ++n)
          op[n * 16] = acc[m][n][r];
      }
    }
  }
}

// ---------------- Path B (fallback, small workspace): round-2 kernels ----------------

__global__ __launch_bounds__(256, 2) void gemm1B(
    const float* __restrict__ x, const float* __restrict__ w1,
    const float* __restrict__ w3, const int* __restrict__ counts,
    const int* __restrict__ lists, u16* __restrict__ G) {
  __shared__ __align__(16) u16 As[128 * LDP];
  __shared__ __align__(16) u16 B1s[128 * LDP];
  __shared__ __align__(16) u16 B3s[128 * LDP];
  __shared__ int toks[128];

  const int e = blockIdx.z;
  int cnt = counts[e];
  if ((unsigned)cnt > CAP) cnt = 0;
  const int m0 = blockIdx.y * 128;
  if (m0 >= cnt) return;
  const int n0 = blockIdx.x * 128;
  const int tid = threadIdx.x;

  if (tid < 128) {
    int r = m0 + tid;
    int it = lists[e * CAP + (r < cnt ? r : 0)];
    toks[tid] = ((unsigned)it < NITEM) ? it : 0;
  }
  __syncthreads();

  const int lane = tid & 63;
  const int wr = ((tid >> 7) & 1) * 64;
  const int wc = ((tid >> 6) & 1) * 64;
  const int lr = lane & 15;
  const int kg = lane >> 4;
  const int arow = tid >> 3;
  const int c8 = (tid & 7) * 8;

  const float* xsrc[4];
#pragma unroll
  for (int p = 0; p < 4; ++p)
    xsrc[p] = x + (size_t)(toks[p * 32 + arow] >> 1) * DIM + c8;
  const float* w1p = w1 + ((size_t)e * HID + n0 + arow) * DIM + c8;
  const float* w3p = w3 + ((size_t)e * HID + n0 + arow) * DIM + c8;

  f32x4 acc1[4][4] = {};
  f32x4 acc3[4][4] = {};

  for (int k0 = 0; k0 < DIM; k0 += 64) {
#pragma unroll
    for (int p = 0; p < 4; ++p) {
      float4 v0 = *(const float4*)(xsrc[p] + k0);
      float4 v1 = *(const float4*)(xsrc[p] + k0 + 4);
      uint4 u;
      u.x = pk2(v0.x, v0.y); u.y = pk2(v0.z, v0.w);
      u.z = pk2(v1.x, v1.y); u.w = pk2(v1.z, v1.w);
      *(uint4*)&As[(p * 32 + arow) * LDP + c8] = u;
    }
#pragma unroll
    for (int p = 0; p < 4; ++p) {
      float4 v0 = *(const float4*)(w1p + (size_t)(p * 32) * DIM + k0);
      float4 v1 = *(const float4*)(w1p + (size_t)(p * 32) * DIM + k0 + 4);
      uint4 u;
      u.x = pk2(v0.x, v0.y); u.y = pk2(v0.z, v0.w);
      u.z = pk2(v1.x, v1.y); u.w = pk2(v1.z, v1.w);
      *(uint4*)&B1s[(p * 32 + arow) * LDP + c8] = u;
      v0 = *(const float4*)(w3p + (size_t)(p * 32) * DIM + k0);
      v1 = *(const float4*)(w3p + (size_t)(p * 32) * DIM + k0 + 4);
      u.x = pk2(v0.x, v0.y); u.y = pk2(v0.z, v0.w);
      u.z = pk2(v1.x, v1.y); u.w = pk2(v1.z, v1.w);
      *(uint4*)&B3s[(p * 32 + arow) * LDP + c8] = u;
    }
    __syncthreads();
#pragma unroll
    for (int kk = 0; kk < 2; ++kk) {
      const int ko = kk * 32 + kg * 8;
      bf16x8 a[4];
#pragma unroll
      for (int m = 0; m < 4; ++m)
        a[m] = *(const bf16x8*)&As[(wr + m * 16 + lr) * LDP + ko];
#pragma unroll
      for (int n = 0; n < 4; ++n) {
        bf16x8 b1 = *(const bf16x8*)&B1s[(wc + n * 16 + lr) * LDP + ko];
        bf16x8 b3 = *(const bf16x8*)&B3s[(wc + n * 16 + lr) * LDP + ko];
#pragma unroll
        for (int m = 0; m < 4; ++m) {
          acc1[m][n] = __builtin_amdgcn_mfma_f32_16x16x32_bf16(a[m], b1, acc1[m][n], 0, 0, 0);
          acc3[m][n] = __builtin_amdgcn_mfma_f32_16x16x32_bf16(a[m], b3, acc3[m][n], 0, 0, 0);
        }
      }
    }
    __syncthreads();
  }

#pragma unroll
  for (int m = 0; m < 4; ++m) {
#pragma unroll
    for (int r = 0; r < 4; ++r) {
      const int row = wr + m * 16 + kg * 4 + r;
      if (m0 + row < cnt) {
        const int it = toks[row];
        u16* gp = G + (size_t)it * HID + n0 + wc + lr;
#pragma unroll
        for (int n = 0; n < 4; ++n) {
          float v1 = acc1[m][n][r];
          float v3 = acc3[m][n][r];
          float s = v1 / (1.f + __expf(-v1)) * v3;
          gp[n * 16] = f2bf(s);
        }
      }
    }
  }
}

__global__ __launch_bounds__(256, 2) void gemm2B(
    const u16* __restrict__ G, const float* __restrict__ w2,
    const int* __restrict__ counts, const int* __restrict__ lists,
    float* __restrict__ out) {
  __shared__ __align__(16) u16 As[128 * LDP];
  __shared__ __align__(16) u16 Bs[128 * LDP];
  __shared__ int toks[128];

  const int e = blockIdx.z;
  int cnt = counts[e];
  if ((unsigned)cnt > CAP) cnt = 0;
  const int m0 = blockIdx.y * 128;
  if (m0 >= cnt) return;
  const int n0 = blockIdx.x * 128;
  const int tid = threadIdx.x;

  if (tid < 128) {
    int r = m0 + tid;
    int it = lists[e * CAP + (r < cnt ? r : 0)];
    toks[tid] = ((unsigned)it < NITEM) ? it : 0;
  }
  __syncthreads();

  const int lane = tid & 63;
  const int wr = ((tid >> 7) & 1) * 64;
  const int wc = ((tid >> 6) & 1) * 64;
  const int lr = lane & 15;
  const int kg = lane >> 4;
  const int arow = tid >> 3;
  const int c8 = (tid & 7) * 8;
  const int brow = tid >> 5;
  const int d4 = (tid & 31) * 4;

  const u16* asrc[4];
#pragma unroll
  for (int p = 0; p < 4; ++p)
    asrc[p] = G + (size_t)toks[p * 32 + arow] * HID + c8;
  const float* bsrc = w2 + ((size_t)e * HID) * DIM + n0 + d4;

  f32x4 acc[4][4] = {};

  for (int k0 = 0; k0 < HID; k0 += 64) {
#pragma unroll
    for (int p = 0; p < 4; ++p) {
      uint4 u = *(const uint4*)(asrc[p] + k0);
      *(uint4*)&As[(p * 32 + arow) * LDP + c8] = u;
    }
#pragma unroll
    for (int p = 0; p < 8; ++p) {
      const int hl = p * 8 + brow;
      float4 v = *(const float4*)(bsrc + (size_t)(k0 + hl) * DIM);
      Bs[(d4 + 0) * LDP + hl] = f2bf(v.x);
      Bs[(d4 + 1) * LDP + hl] = f2bf(v.y);
      Bs[(d4 + 2) * LDP + hl] = f2bf(v.z);
      Bs[(d4 + 3) * LDP + hl] = f2bf(v.w);
    }
    __syncthreads();
#pragma unroll
    for (int kk = 0; kk < 2; ++kk) {
      const int ko = kk * 32 + kg * 8;
      bf16x8 a[4];
#pragma unroll
      for (int m = 0; m < 4; ++m)
        a[m] = *(const bf16x8*)&As[(wr + m * 16 + lr) * LDP + ko];
#pragma unroll
      for (int n = 0; n < 4; ++n) {
        bf16x8 b = *(const bf16x8*)&Bs[(wc + n * 16 + lr) * LDP + ko];
#pragma unroll
        for (int m = 0; m < 4; ++m)
          acc[m][n] = __builtin_amdgcn_mfma_f32_16x16x32_bf16(a[m], b, acc[m][n], 0, 0, 0);
      }
    }
    __syncthreads();
  }

#pragma unroll
  for (int m = 0; m < 4; ++m) {
#pragma unroll
    for (int r = 0; r < 4; ++r) {
      const int row = wr + m * 16 + kg * 4 + r;
      if (m0 + row < cnt) {
        const int it = toks[row];
        float* op = out + (size_t)it * DIM + n0 + wc + lr;
#pragma unroll
        for (int n = 0; n < 4; ++n)
          op[n * 16] = acc[m][n][r];
      }
    }
  }
}

extern "C" void kernel_launch(void* const* d_in, const int* in_sizes, int n_in,
                              void* d_out, int out_size, void* d_ws, size_t ws_size,
                              hipStream_t stream) {
  (void)in_sizes; (void)n_in; (void)out_size;
  const float* x  = (const float*)d_in[0];
  const int*   ei = (const int*)d_in[1];
  const float* w1 = (const float*)d_in[2];
  const float* w2 = (const float*)d_in[3];
  const float* w3 = (const float*)d_in[4];
  float* out = (float*)d_out;

  char* ws = (char*)d_ws;

  // Path A layout: G | xb | w2t | counts | lists  (~73.5 MB)
  const size_t oG = 0;
  const size_t oXB = 23068672u;
  const size_t oW2T = oXB + 4194304u;
  const size_t oCNT = oW2T + 46137344u;
  const size_t oLST = oCNT + 64u;
  const size_t needA = oLST + 131072u;

  if (ws_size >= needA) {
    u16* G      = (u16*)(ws + oG);
    u16* xb     = (u16*)(ws + oXB);
    u16* w2t    = (u16*)(ws + oW2T);
    int* counts = (int*)(ws + oCNT);
    int* lists  = (int*)(ws + oLST);

    zero8<<<1, 64, 0, stream>>>(counts);
    bucket<<<NITEM / 256, 256, 0, stream>>>(ei, counts, lists);
    cvt8<<<(NTOK * DIM / 8) / 256, 256, 0, stream>>>(x, xb, NTOK * DIM / 8);
    gemm1I<<<44 * 8 * 16, 256, 0, stream>>>(xb, w1, w3, counts, lists, G);
    tw2<<<dim3(DIM / 64, HID / 64, NEXP), 256, 0, stream>>>(w2, w2t);
    gemm2F<<<16 * 8 * 32, 256, 0, stream>>>(G, w2t, counts, lists, out);
  } else {
    // fallback: compact workspace, on-the-fly conversion (round-2 path)
    u16* G      = (u16*)ws;
    int* counts = (int*)(ws + 23068672u);
    int* lists  = (int*)(ws + 23068736u);

    zero8<<<1, 64, 0, stream>>>(counts);
    bucket<<<NITEM / 256, 256, 0, stream>>>(ei, counts, lists);
    gemm1B<<<dim3(HID / 128, CAP / 128, NEXP), 256, 0, stream>>>(x, w1, w3, counts, lists, G);
    gemm2B<<<dim3(DIM / 128, CAP / 128, NEXP), 256, 0, stream>>>(G, w2, counts, lists, out);
  }
}